// Round 17
// baseline (25.976 us; speedup 1.0000x reference)
//
#include <hip/hip_runtime.h>

typedef _Float16 f16;
typedef f16 f16x4 __attribute__((ext_vector_type(4)));
typedef f16 f16x8 __attribute__((ext_vector_type(8)));
typedef float f32x4 __attribute__((ext_vector_type(4)));

constexpr int Bc = 32, Nc = 1024, Dc = 64, Hc = 4, Ec = 16;
constexpr int HPL = 1032;  // attn LDS hv pitch (f16) = 129 float4 rows

// ---------------------------------------------------------------------------
// Kernel 1: MFMA proj with COALESCED stores (fixes r12's diagnosed flaw:
// 8B/lane scatter at 2KB stride). Grid 1024 x 256thr (4 blocks/CU).
// Wave w: 2 MFMA tiles (rows n0+w*32+t*16). D(f32x4) -> f16 -> LDS T[16][136]
// -> one float4/thread coalesced store. s = input.(W@a) f32 dot, half-row
// split + shfl_xor(1) (numerics validated r11/r12).
// ---------------------------------------------------------------------------
__global__ __launch_bounds__(256) void gat_projm2(const float* __restrict__ input,
                                                  const float* __restrict__ W,
                                                  const float* __restrict__ a,
                                                  f16* __restrict__ h16t,
                                                  float* __restrict__ s_src,
                                                  float* __restrict__ s_dst) {
    __shared__ float wa_lds[2][Dc];            // 512 B (f32 W@a)
    __shared__ alignas(16) f16 T[Ec][136];     // 4.25 KB (128 + 8 pad)

    const int tid  = threadIdx.x;
    const int blk  = blockIdx.x;            // 0..1023
    const int bh   = blk >> 3;
    const int hh   = bh & (Hc - 1);
    const int b    = bh >> 2;
    const int n0   = (blk & 7) * 128;
    const int lane = tid & 63;
    const int wave = tid >> 6;              // 0..3
    const int row  = lane & 15;
    const int quad = lane >> 4;

    // ---- wa[d] (two 16-dots per d, threads 0..127) ----
    if (tid < 2 * Dc) {
        const int d = tid & (Dc - 1), which = tid >> 6;
        const float* wr = W + hh * Dc * Ec + d * Ec;
        const float* av = a + which * Ec;
        float acc = 0.f;
#pragma unroll
        for (int e = 0; e < Ec; ++e) acc = fmaf(wr[e], av[e], acc);
        wa_lds[which][d] = acc;
    }

    // ---- W B-fragments (f16): col(e) = row, k(d) = quad*8+j (+32) ----
    f16x8 bW0, bW1;
    {
        const float* wp = W + hh * Dc * Ec + row;
#pragma unroll
        for (int j = 0; j < 8; ++j) {
            bW0[j] = (f16)wp[(quad * 8 + j) * Ec];
            bW1[j] = (f16)wp[(32 + quad * 8 + j) * Ec];
        }
    }

    // ---- 2 MFMA tiles per wave -> f16 into LDS T ----
#pragma unroll
    for (int t = 0; t < 2; ++t) {
        const int nl = wave * 32 + t * 16;           // tile base within block
        const float* ip = input + ((size_t)b * Nc + n0 + nl + row) * Dc;
        f16x8 x0, x1;
#pragma unroll
        for (int j = 0; j < 8; ++j) {
            x0[j] = (f16)ip[quad * 8 + j];
            x1[j] = (f16)ip[32 + quad * 8 + j];
        }
        f32x4 hD = {};
        hD = __builtin_amdgcn_mfma_f32_16x16x32_f16(x0, bW0, hD, 0, 0, 0);
        hD = __builtin_amdgcn_mfma_f32_16x16x32_f16(x1, bW1, hD, 0, 0, 0);
        // D: n-row = nl + quad*4 + r, e-col = row (m89; validated r12)
        f16x4 hp;
#pragma unroll
        for (int r = 0; r < 4; ++r) hp[r] = (f16)hD[r];
        *(f16x4*)(&T[row][nl + quad * 4]) = hp;
    }
    __syncthreads();

    // ---- coalesced h16t stores: one float4 chunk per thread ----
    {
        const int e2 = tid >> 4;          // 0..15
        const int ch = tid & 15;          // 16 chunks of 8 f16 = 128 n
        *(float4*)(h16t + (size_t)bh * Ec * Nc + (size_t)e2 * Nc + n0 + ch * 8) =
            *(const float4*)(&T[e2][ch * 8]);
    }

    // ---- s (f32): thread -> row nl = tid>>1, d-half = (tid&1)*32 ----
    {
        const int nl = tid >> 1;
        const int dh = (tid & 1) * 8;     // float4 index offset
        const float4* xr  = (const float4*)(input + ((size_t)b * Nc + n0 + nl) * Dc) + dh;
        const float4* wdp = (const float4*)wa_lds[0] + dh;
        const float4* wsp = (const float4*)wa_lds[1] + dh;
        float sd = 0.f, ss = 0.f;
#pragma unroll
        for (int d4 = 0; d4 < 8; ++d4) {
            float4 x = xr[d4], wd = wdp[d4], wsx = wsp[d4];
            sd = fmaf(x.x, wd.x,  fmaf(x.y, wd.y,  fmaf(x.z, wd.z,  fmaf(x.w, wd.w,  sd))));
            ss = fmaf(x.x, wsx.x, fmaf(x.y, wsx.y, fmaf(x.z, wsx.z, fmaf(x.w, wsx.w, ss))));
        }
        sd += __shfl_xor(sd, 1, 64);
        ss += __shfl_xor(ss, 1, 64);
        if ((tid & 1) == 0) {
            s_dst[bh * Nc + n0 + nl] = sd;
            s_src[bh * Nc + n0 + nl] = ss;
        }
    }
}

// ---------------------------------------------------------------------------
// Kernel 2: BYTE-IDENTICAL round-14 attn10 (best measured: 23.84us total).
// P_ij = v_j * max(w_j, C_i) exact; hv = v*h in B; 4 pk_max + 2 MFMA per (it,kt).
// ---------------------------------------------------------------------------
__global__ __launch_bounds__(512) void gat_attn10(const f16* __restrict__ h16t,
                                                  const float* __restrict__ s_src,
                                                  const float* __restrict__ s_dst,
                                                  float* __restrict__ out) {
    __shared__ alignas(16) f16 hv_t[Ec * HPL];   // 33 KB (v-scaled h)
    __shared__ alignas(16) f16 w_lds[Nc];        // 2 KB
    __shared__ alignas(16) f16 v_lds[Nc];        // 2 KB
    __shared__ float red[8];

    const int bh    = blockIdx.x;      // 0..127
    const int ihalf = blockIdx.y;      // 0..1
    const int tid   = threadIdx.x;
    const int lane  = tid & 63;
    const int wave  = tid >> 6;        // 0..7
    const int row   = lane & 15;
    const int quad  = lane >> 4;

    // ---- issue h chunk loads early (latency hides under reduce/exp) ----
    f16x8 h8[4];
    {
        const float4* src = (const float4*)(h16t + (size_t)bh * Ec * Nc);
#pragma unroll
        for (int cc = 0; cc < 4; ++cc) {
            float4 t = src[cc * 512 + tid];
            h8[cc] = *(f16x8*)&t;
        }
    }

    // ---- block max of s_dst ----
    const float sd0 = s_dst[bh * Nc + tid];
    const float sd1 = s_dst[bh * Nc + 512 + tid];
    {
        float m = fmaxf(sd0, sd1);
#pragma unroll
        for (int off = 1; off < 64; off <<= 1) m = fmaxf(m, __shfl_xor(m, off, 64));
        if (lane == 0) red[wave] = m;
    }
    __syncthreads();
    float maxd = red[0];
#pragma unroll
    for (int w = 1; w < 8; ++w) maxd = fmaxf(maxd, red[w]);

    // ---- w, v into LDS ----
    w_lds[tid]       = (f16)__expf(0.8f * (sd0 - maxd));
    w_lds[512 + tid] = (f16)__expf(0.8f * (sd1 - maxd));
    v_lds[tid]       = (f16)__expf(0.2f * (sd0 - maxd));
    v_lds[512 + tid] = (f16)__expf(0.2f * (sd1 - maxd));

    // ---- per-row C_i ----
    const int ibase = ihalf * 512 + wave * 64;
    f16x8 C8[4];
#pragma unroll
    for (int it = 0; it < 4; ++it) {
        const float si = s_src[bh * Nc + ibase + it * 16 + row];
        const float c1 = si + maxd;
        const float Cf = (c1 >= 0.f) ? __expf(-0.8f * c1) : 1.0f;
        const f16 ch = (f16)Cf;
        C8[it] = (f16x8){ch, ch, ch, ch, ch, ch, ch, ch};
    }
    __syncthreads();   // v_lds ready for hv build

    // ---- build hv = v * h into LDS ----
    {
        float4* dst = (float4*)hv_t;
#pragma unroll
        for (int cc = 0; cc < 4; ++cc) {
            const int c  = cc * 512 + tid;     // 0..2047
            const int e  = c >> 7;
            const int jc = c & 127;
            const f16x8 v8 = *(const f16x8*)(&v_lds[jc * 8]);
            f16x8 hv = h8[cc] * v8;            // 4 pk muls
            dst[e * 129 + jc] = *(float4*)&hv;
        }
    }
    __syncthreads();

    f32x4 accN[4] = {};
    f32x4 accD[4] = {};

    const f16* wp = w_lds + quad * 8;
    const f16* vp = v_lds + quad * 8;
    const f16* bp = hv_t + row * HPL + quad * 8;

#pragma unroll 4
    for (int kt = 0; kt < 32; ++kt) {
        const f16x8 w8  = *(const f16x8*)(wp + kt * 32);
        const f16x8 v8  = *(const f16x8*)(vp + kt * 32);
        const f16x8 hv8 = *(const f16x8*)(bp + kt * 32);
#pragma unroll
        for (int it = 0; it < 4; ++it) {
            const f16x8 pm = __builtin_elementwise_max(w8, C8[it]);   // 4 pk instrs
            accN[it] = __builtin_amdgcn_mfma_f32_16x16x32_f16(pm, hv8, accN[it], 0, 0, 0);
            accD[it] = __builtin_amdgcn_mfma_f32_16x16x32_f16(pm, v8,  accD[it], 0, 0, 0);
        }
    }

    // ---- epilogue: D row = quad*4 + r, col = row ----
#pragma unroll
    for (int it = 0; it < 4; ++it) {
#pragma unroll
        for (int r = 0; r < 4; ++r) {
            const float inv = __builtin_amdgcn_rcpf(accD[it][r]);
            const int i = ibase + it * 16 + quad * 4 + r;
            out[((size_t)(bh * Nc + i)) * Ec + row] = accN[it][r] * inv;
        }
    }
}

extern "C" void kernel_launch(void* const* d_in, const int* in_sizes, int n_in,
                              void* d_out, int out_size, void* d_ws, size_t ws_size,
                              hipStream_t stream) {
    const float* input = (const float*)d_in[0];
    // d_in[1] = adj : UNUSED by the reference
    const float* W = (const float*)d_in[2];
    const float* a = (const float*)d_in[3];
    float* out = (float*)d_out;

    char* ws = (char*)d_ws;
    f16*   h16t  = (f16*)(ws);                       // 4,194,304 B
    float* s_src = (float*)(ws + 4194304);           // 524,288 B
    float* s_dst = (float*)(ws + 4194304 + 524288);  // 524,288 B

    gat_projm2<<<dim3(1024), dim3(256), 0, stream>>>(input, W, a, h16t, s_src, s_dst);
    gat_attn10<<<dim3(Bc * Hc, 2), dim3(512), 0, stream>>>(h16t, s_src, s_dst, out);
}

// Round 18
// 23.896 us; speedup vs baseline: 1.0870x; 1.0870x over previous
//
#include <hip/hip_runtime.h>

typedef _Float16 f16;
typedef f16 f16x8 __attribute__((ext_vector_type(8)));
typedef float f32x4 __attribute__((ext_vector_type(4)));

constexpr int Bc = 32, Nc = 1024, Dc = 64, Hc = 4, Ec = 16;
constexpr int HPL = 1032;  // attn LDS hv pitch (f16) = 129 float4 rows

// ---------------------------------------------------------------------------
// Kernel 1: round-13/14 proj2 EXACT (measured best total: 23.84us).
// 1024 blocks x 256 thr (4 blocks/CU), thread = (n, e-half), 512-FMA chains,
// s via shfl_xor(1), h16t stored transposed via LDS + coalesced float4.
// ---------------------------------------------------------------------------
__global__ __launch_bounds__(256) void gat_proj2(const float* __restrict__ input,
                                                 const float* __restrict__ W,
                                                 const float* __restrict__ a,
                                                 f16* __restrict__ h16t,
                                                 float* __restrict__ s_src,
                                                 float* __restrict__ s_dst) {
    __shared__ float W_lds[Dc * Ec];          // 4 KB
    __shared__ float a_lds[2 * Ec];
    __shared__ alignas(16) f16 T[Ec][136];    // 128 + 8 pad

    const int tid  = threadIdx.x;
    const int blk  = blockIdx.x;           // 0..1023
    const int bh   = blk >> 3;             // measured-best decode
    const int hh   = bh & (Hc - 1);
    const int b    = bh >> 2;
    const int n0   = (blk & 7) * 128;
    const int half = tid & 1;
    const int nl   = tid >> 1;
    const int n    = n0 + nl;

    ((float4*)W_lds)[tid] = ((const float4*)(W + hh * Dc * Ec))[tid];
    if (tid < 2 * Ec) a_lds[tid] = a[tid];
    __syncthreads();

    const float4* in_row = (const float4*)(input + ((size_t)b * Nc + n) * Dc);

    float acc[8];
#pragma unroll
    for (int e = 0; e < 8; ++e) acc[e] = 0.f;

#pragma unroll
    for (int d4 = 0; d4 < Dc / 4; ++d4) {
        float4 x = in_row[d4];
        float xs[4] = {x.x, x.y, x.z, x.w};
#pragma unroll
        for (int k = 0; k < 4; ++k) {
            const float xv = xs[k];
            const float* wrow = &W_lds[(d4 * 4 + k) * Ec + half * 8];
#pragma unroll
            for (int e = 0; e < 8; ++e) acc[e] = fmaf(xv, wrow[e], acc[e]);
        }
    }

    {
        float sd = 0.f, ss = 0.f;
#pragma unroll
        for (int e = 0; e < 8; ++e) {
            sd = fmaf(acc[e], a_lds[half * 8 + e],      sd);
            ss = fmaf(acc[e], a_lds[16 + half * 8 + e], ss);
        }
        sd += __shfl_xor(sd, 1, 64);
        ss += __shfl_xor(ss, 1, 64);
        if (half == 0) {
            s_dst[bh * Nc + n] = sd;
            s_src[bh * Nc + n] = ss;
        }
    }

#pragma unroll
    for (int e = 0; e < 8; ++e) T[half * 8 + e][nl] = (f16)acc[e];
    __syncthreads();

    {
        const int e2 = tid >> 4;
        const int ch = tid & 15;
        *(float4*)(h16t + (size_t)bh * Ec * Nc + (size_t)e2 * Nc + n0 + ch * 8) =
            *(const float4*)(&T[e2][ch * 8]);
    }
}

// ---------------------------------------------------------------------------
// Kernel 2: round-14 attn10 EXACT. P_ij = v_j * max(w_j, C_i) (exact refactor
// of softmax(lrelu) via exp∘max = max∘exp); hv = v*h folded into B-operand;
// inner loop = 4 pk_max + 2 MFMA per (it,kt).
// ---------------------------------------------------------------------------
__global__ __launch_bounds__(512) void gat_attn10(const f16* __restrict__ h16t,
                                                  const float* __restrict__ s_src,
                                                  const float* __restrict__ s_dst,
                                                  float* __restrict__ out) {
    __shared__ alignas(16) f16 hv_t[Ec * HPL];   // 33 KB (v-scaled h)
    __shared__ alignas(16) f16 w_lds[Nc];        // 2 KB
    __shared__ alignas(16) f16 v_lds[Nc];        // 2 KB
    __shared__ float red[8];

    const int bh    = blockIdx.x;      // 0..127
    const int ihalf = blockIdx.y;      // 0..1
    const int tid   = threadIdx.x;
    const int lane  = tid & 63;
    const int wave  = tid >> 6;        // 0..7
    const int row   = lane & 15;
    const int quad  = lane >> 4;

    // ---- issue h chunk loads early (latency hides under reduce/exp) ----
    f16x8 h8[4];
    {
        const float4* src = (const float4*)(h16t + (size_t)bh * Ec * Nc);
#pragma unroll
        for (int cc = 0; cc < 4; ++cc) {
            float4 t = src[cc * 512 + tid];
            h8[cc] = *(f16x8*)&t;
        }
    }

    // ---- block max of s_dst ----
    const float sd0 = s_dst[bh * Nc + tid];
    const float sd1 = s_dst[bh * Nc + 512 + tid];
    {
        float m = fmaxf(sd0, sd1);
#pragma unroll
        for (int off = 1; off < 64; off <<= 1) m = fmaxf(m, __shfl_xor(m, off, 64));
        if (lane == 0) red[wave] = m;
    }
    __syncthreads();
    float maxd = red[0];
#pragma unroll
    for (int w = 1; w < 8; ++w) maxd = fmaxf(maxd, red[w]);

    // ---- w, v into LDS ----
    w_lds[tid]       = (f16)__expf(0.8f * (sd0 - maxd));
    w_lds[512 + tid] = (f16)__expf(0.8f * (sd1 - maxd));
    v_lds[tid]       = (f16)__expf(0.2f * (sd0 - maxd));
    v_lds[512 + tid] = (f16)__expf(0.2f * (sd1 - maxd));

    // ---- per-row C_i ----
    const int ibase = ihalf * 512 + wave * 64;
    f16x8 C8[4];
#pragma unroll
    for (int it = 0; it < 4; ++it) {
        const float si = s_src[bh * Nc + ibase + it * 16 + row];
        const float c1 = si + maxd;
        const float Cf = (c1 >= 0.f) ? __expf(-0.8f * c1) : 1.0f;
        const f16 ch = (f16)Cf;
        C8[it] = (f16x8){ch, ch, ch, ch, ch, ch, ch, ch};
    }
    __syncthreads();   // v_lds ready for hv build

    // ---- build hv = v * h into LDS ----
    {
        float4* dst = (float4*)hv_t;
#pragma unroll
        for (int cc = 0; cc < 4; ++cc) {
            const int c  = cc * 512 + tid;     // 0..2047
            const int e  = c >> 7;
            const int jc = c & 127;
            const f16x8 v8 = *(const f16x8*)(&v_lds[jc * 8]);
            f16x8 hv = h8[cc] * v8;            // 4 pk muls
            dst[e * 129 + jc] = *(float4*)&hv;
        }
    }
    __syncthreads();

    f32x4 accN[4] = {};
    f32x4 accD[4] = {};

    const f16* wp = w_lds + quad * 8;
    const f16* vp = v_lds + quad * 8;
    const f16* bp = hv_t + row * HPL + quad * 8;

#pragma unroll 4
    for (int kt = 0; kt < 32; ++kt) {
        const f16x8 w8  = *(const f16x8*)(wp + kt * 32);
        const f16x8 v8  = *(const f16x8*)(vp + kt * 32);
        const f16x8 hv8 = *(const f16x8*)(bp + kt * 32);
#pragma unroll
        for (int it = 0; it < 4; ++it) {
            const f16x8 pm = __builtin_elementwise_max(w8, C8[it]);   // 4 pk instrs
            accN[it] = __builtin_amdgcn_mfma_f32_16x16x32_f16(pm, hv8, accN[it], 0, 0, 0);
            accD[it] = __builtin_amdgcn_mfma_f32_16x16x32_f16(pm, v8,  accD[it], 0, 0, 0);
        }
    }

    // ---- epilogue: D row = quad*4 + r, col = row ----
#pragma unroll
    for (int it = 0; it < 4; ++it) {
#pragma unroll
        for (int r = 0; r < 4; ++r) {
            const float inv = __builtin_amdgcn_rcpf(accD[it][r]);
            const int i = ibase + it * 16 + quad * 4 + r;
            out[((size_t)(bh * Nc + i)) * Ec + row] = accN[it][r] * inv;
        }
    }
}

extern "C" void kernel_launch(void* const* d_in, const int* in_sizes, int n_in,
                              void* d_out, int out_size, void* d_ws, size_t ws_size,
                              hipStream_t stream) {
    const float* input = (const float*)d_in[0];
    // d_in[1] = adj : UNUSED by the reference
    const float* W = (const float*)d_in[2];
    const float* a = (const float*)d_in[3];
    float* out = (float*)d_out;

    char* ws = (char*)d_ws;
    f16*   h16t  = (f16*)(ws);                       // 4,194,304 B
    float* s_src = (float*)(ws + 4194304);           // 524,288 B
    float* s_dst = (float*)(ws + 4194304 + 524288);  // 524,288 B

    gat_proj2<<<dim3(1024), dim3(256), 0, stream>>>(input, W, a, h16t, s_src, s_dst);
    gat_attn10<<<dim3(Bc * Hc, 2), dim3(512), 0, stream>>>(h16t, s_src, s_dst, out);
}